// Round 7
// baseline (418.375 us; speedup 1.0000x reference)
//
#include <hip/hip_runtime.h>
#include <hip/hip_bf16.h>
#include <math.h>

#define B_ 8
#define R_ 1024
#define D_ 256
#define H_ 8
#define L_ 2
#define E_ 32768
#define FF_ 1024
#define NEGV (-1000000000.0f)

typedef short bf16x8 __attribute__((ext_vector_type(8)));
typedef float f32x4 __attribute__((ext_vector_type(4)));

__device__ __forceinline__ unsigned short f2b(float f){
  unsigned int u = __float_as_uint(f);
  u += 0x7fffu + ((u >> 16) & 1u);
  return (unsigned short)(u >> 16);
}
__device__ __forceinline__ float b2f(unsigned short u){
  return __uint_as_float((unsigned int)u << 16);
}
__device__ __forceinline__ unsigned int pk_bf16(float lo, float hi){
  unsigned int r;
  asm volatile("v_cvt_pk_bf16_f32 %0, %1, %2" : "=v"(r) : "v"(lo), "v"(hi));
  return r;
}

#define ASYNC_COPY16(gp, lp) \
  __builtin_amdgcn_global_load_lds((const __attribute__((address_space(1))) void*)(gp), \
                                   (__attribute__((address_space(3))) void*)(lp), 16, 0, 0)

// ---------------- mask construction (f32, exact reference semantics) ----------------

__global__ void detect_bool(const unsigned char* __restrict__ km, int* __restrict__ flag){
  int i = blockIdx.x*256 + threadIdx.x;
  int hit = ((i & 3) != 0) && (km[i] != 0);
  if (__ballot(hit) != 0ull && (threadIdx.x & 63) == 0) atomicOr(flag, 1);
}

__global__ void mask_fill(float* __restrict__ mask){
  size_t i = ((size_t)blockIdx.x*256 + threadIdx.x)*4;
  int row = (int)((i >> 10) & 1023);
  int col = (int)(i & 1023);
  float4 v;
  v.x = (row == col+0) ? 0.0f : NEGV;
  v.y = (row == col+1) ? 0.0f : NEGV;
  v.z = (row == col+2) ? 0.0f : NEGV;
  v.w = (row == col+3) ? 0.0f : NEGV;
  *(float4*)&mask[i] = v;
}

__device__ __forceinline__ int keep_of(const unsigned char* km, const int* flag, int tid){
  return flag[0] ? (int)km[tid] : (int)km[(size_t)tid*4];
}

__global__ void edge_base(const int* __restrict__ ei, const unsigned char* __restrict__ km,
                          const int* __restrict__ flag, float* __restrict__ mask){
  int tid = blockIdx.x*256 + threadIdx.x;
  int b = tid >> 15, e = tid & (E_-1);
  if (keep_of(km, flag, tid)){
    int src = ei[(size_t)b*2*E_ + e];
    int dst = ei[(size_t)b*2*E_ + E_ + e];
    mask[((size_t)b*R_ + src)*R_ + dst] = 0.0f;
  }
}

__global__ void edge_bias(const int* __restrict__ ei, const int* __restrict__ rid,
                          const unsigned char* __restrict__ km, const int* __restrict__ flag,
                          const float* __restrict__ rb, float* __restrict__ mask){
  int tid = blockIdx.x*256 + threadIdx.x;
  int b = tid >> 15, e = tid & (E_-1);
  if (keep_of(km, flag, tid)){
    int src = ei[(size_t)b*2*E_ + e];
    int dst = ei[(size_t)b*2*E_ + E_ + e];
    atomicAdd(&mask[((size_t)b*R_ + src)*R_ + dst], rb[rid[tid]]);
  }
}

// ---------------- fused dtype converts (1 launch: mask + node + 4 weights) -------
// blocks: [0,8192) mask | [8192,10240) node | +384 Wqkv | +128 Wo | +512 W1 | +512 W2
__global__ __launch_bounds__(256) void cvt_all(const float* __restrict__ maskf,
    const float* __restrict__ node, const float* __restrict__ Wqkv,
    const float* __restrict__ Wo, const float* __restrict__ W1, const float* __restrict__ W2,
    unsigned short* __restrict__ maskbf, unsigned short* __restrict__ x_bf,
    unsigned short* __restrict__ wqkv_b, unsigned short* __restrict__ wo_b,
    unsigned short* __restrict__ w1_b, unsigned short* __restrict__ w2_b)
{
  int bid = blockIdx.x;
  const float* s; unsigned short* d; int base;
  if      (bid < 8192)  { s = maskf; d = maskbf; base = bid; }
  else if (bid < 10240) { s = node;  d = x_bf;   base = bid - 8192; }
  else if (bid < 10624) { s = Wqkv;  d = wqkv_b; base = bid - 10240; }
  else if (bid < 10752) { s = Wo;    d = wo_b;   base = bid - 10624; }
  else if (bid < 11264) { s = W1;    d = w1_b;   base = bid - 10752; }
  else                  { s = W2;    d = w2_b;   base = bid - 11264; }
  size_t i = ((size_t)base*256 + threadIdx.x)*4;
  float4 v = *(const float4*)&s[i];
  ushort4 o;
  o.x = f2b(v.x); o.y = f2b(v.y); o.z = f2b(v.z); o.w = f2b(v.w);
  *(ushort4*)&d[i] = o;
}

// ---------------- GEMM: C[M,N] = A[M,K] * B[N,K]^T ----------------
// MODE 0: bf16 out +bias | MODE 1: bf16 PARTIAL out, NO bias (split-K) | MODE 2: bf16 out gelu(+bias)
template<int MODE, int BN, int KS>
__global__ __launch_bounds__(256) void gemm_bt(const unsigned short* __restrict__ A,
    const unsigned short* __restrict__ Bw, const float* __restrict__ bias,
    void* __restrict__ Cout, int M, int N, int K)
{
  constexpr int NI = BN/32;
  constexpr int NCH = 8 + BN/16;
  constexpr int CPW = NCH/4;
  __shared__ unsigned short As[128*32];
  __shared__ unsigned short Bs[BN*32];
  const int nb = N / BN, mb = M >> 7;
  const int ks = blockIdx.x / (mb*nb);
  const int rem = blockIdx.x % (mb*nb);
  const int bm = rem / nb, bn = rem % nb;
  const int m0 = bm << 7, n0 = bn * BN;
  const int kbeg = ks * (K/KS), kend = kbeg + K/KS;
  const int t = threadIdx.x, lane = t & 63, wid = t >> 6;
  const int wr = wid >> 1, wc = wid & 1;
  const int c = lane & 15, g = lane >> 4;

  f32x4 zz = {0.f,0.f,0.f,0.f};
  f32x4 acc[4][NI];
  #pragma unroll
  for (int mi=0; mi<4; mi++)
    #pragma unroll
    for (int ni=0; ni<NI; ni++) acc[mi][ni] = zz;

  for (int k0 = kbeg; k0 < kend; k0 += 32){
    __syncthreads();
    #pragma unroll
    for (int it=0; it<CPW; ++it){
      int chunk = wid*CPW + it;
      int row16 = lane >> 2, seg = lane & 3;
      if (chunk < 8){
        int row = chunk*16 + row16;
        ASYNC_COPY16(A + (size_t)(m0+row)*K + k0 + seg*8, &As[chunk*512]);
      } else {
        int bch = chunk - 8;
        int row = bch*16 + row16;
        ASYNC_COPY16(Bw + (size_t)(n0+row)*K + k0 + seg*8, &Bs[bch*512]);
      }
    }
    __syncthreads();
    bf16x8 af[4], bfr[NI];
    #pragma unroll
    for (int mi=0; mi<4; mi++) af[mi]  = *(const bf16x8*)&As[(wr*64 + mi*16 + c)*32 + g*8];
    #pragma unroll
    for (int ni=0; ni<NI; ni++) bfr[ni] = *(const bf16x8*)&Bs[(wc*(BN/2) + ni*16 + c)*32 + g*8];
    #pragma unroll
    for (int mi=0; mi<4; mi++)
      #pragma unroll
      for (int ni=0; ni<NI; ni++)
        acc[mi][ni] = __builtin_amdgcn_mfma_f32_16x16x32_bf16(af[mi], bfr[ni], acc[mi][ni], 0,0,0);
  }

  unsigned short* outb = (unsigned short*)Cout + (size_t)ks*M*N;
  #pragma unroll
  for (int mi=0; mi<4; mi++){
    #pragma unroll
    for (int ni=0; ni<NI; ni++){
      int col = n0 + wc*(BN/2) + ni*16 + c;
      float bv = (MODE == 1) ? 0.0f : bias[col];
      #pragma unroll
      for (int r=0; r<4; r++){
        int row = m0 + wr*64 + mi*16 + 4*g + r;
        float v = acc[mi][ni][r] + bv;
        if (MODE == 2) v = 0.5f*v*(1.0f + erff(v*0.70710678f));
        outb[(size_t)row*N + col] = f2b(v);
      }
    }
  }
}

// ---------------- flash attention v3: double-buffered, async reg-staged ----------
// 512 blocks x 512 thr (8 waves). Wave w owns q rows qt*128+w*16+c.
// Per kt: issue K/V loads for kt+1 -> regs; compute kt (QK, mask from regs, softmax,
// shuffle-P, PV); one barrier; write regs -> other LDS buffer.
__global__ __launch_bounds__(512, 2) void attn_kernel(const unsigned short* __restrict__ qkv,
    const unsigned short* __restrict__ maskbf, unsigned short* __restrict__ aout)
{
  __shared__ unsigned short K0[128*36], K1[128*36];   // stride 36
  __shared__ unsigned short V0[32*132], V1[32*132];   // stride 132
  const int blk = blockIdx.x;
  const int qt = blk & 7, h = (blk >> 3) & 7, b = blk >> 6;
  const int t = threadIdx.x, lane = t & 63, w = t >> 6;
  const int c = lane & 15, g = lane >> 4;
  const int qrow = qt*128 + w*16 + c;
  const size_t qbase = (size_t)b*R_*768;
  const float scale = 0.17677669529663689f;   // 1/sqrt(32)

  const int krow = t >> 2, kseg = t & 3;   // K staging: one uint4/thread
  const int vd = t & 31, vgrp = t >> 5;    // V staging: 8 shorts/thread

  bf16x8 qf = *(const bf16x8*)&qkv[qbase + (size_t)qrow*768 + h*32 + g*8];

  f32x4 z4 = {0.f,0.f,0.f,0.f};
  f32x4 oacc[2] = {z4, z4};
  float mrun = -1e30f, lrun = 0.f;
  const int srcA = c + ((lane & 16) << 1);
  const int srcB = srcA + 16;
  const bool hig = (lane >= 32);

  const unsigned short* mrowp = &maskbf[((size_t)b*R_ + qrow)*R_];

  unsigned short* klW = K0; unsigned short* vtW = V0;
  unsigned short* klR = K1; unsigned short* vtR = V1;

  // prologue: stage tile 0, preload mask tile 0
  {
    uint4 kd = *(const uint4*)&qkv[qbase + (size_t)krow*768 + 256 + h*32 + kseg*8];
    __align__(16) unsigned short tv[8];
    #pragma unroll
    for (int j=0; j<8; j++) tv[j] = qkv[qbase + (size_t)(vgrp*8 + j)*768 + 512 + h*32 + vd];
    *(uint4*)&klW[krow*36 + kseg*8] = kd;
    *(uint4*)&vtW[vd*132 + vgrp*8] = *(const uint4*)&tv[0];
  }
  ushort4 mreg[8];
  #pragma unroll
  for (int fc=0; fc<8; ++fc) mreg[fc] = *(const ushort4*)&mrowp[fc*16 + 4*g];
  __syncthreads();

  for (int kt=0; kt<8; ++kt){
    { unsigned short* x_ = klR; klR = klW; klW = x_; }
    { unsigned short* x_ = vtR; vtR = vtW; vtW = x_; }
    const bool more = (kt < 7);

    // issue next-tile K/V global loads (latency hides under compute below)
    uint4 kd;
    __align__(16) unsigned short tv[8];
    if (more){
      const int kv1 = (kt+1)*128;
      kd = *(const uint4*)&qkv[qbase + (size_t)(kv1+krow)*768 + 256 + h*32 + kseg*8];
      #pragma unroll
      for (int j=0; j<8; j++) tv[j] = qkv[qbase + (size_t)(kv1 + vgrp*8 + j)*768 + 512 + h*32 + vd];
    }

    // QK^T from current K buffer
    f32x4 st[8];
    #pragma unroll
    for (int fc=0; fc<8; ++fc){
      bf16x8 kb = *(const bf16x8*)&klR[(fc*16 + c)*36 + g*8];
      st[fc] = __builtin_amdgcn_mfma_f32_16x16x32_bf16(kb, qf, z4, 0,0,0);
    }
    // scale + mask (regs), then immediately issue next mask loads
    #pragma unroll
    for (int fc=0; fc<8; ++fc){
      ushort4 mu = mreg[fc];
      st[fc][0] = st[fc][0]*scale + b2f(mu.x);
      st[fc][1] = st[fc][1]*scale + b2f(mu.y);
      st[fc][2] = st[fc][2]*scale + b2f(mu.z);
      st[fc][3] = st[fc][3]*scale + b2f(mu.w);
    }
    if (more){
      #pragma unroll
      for (int fc=0; fc<8; ++fc) mreg[fc] = *(const ushort4*)&mrowp[(kt+1)*128 + fc*16 + 4*g];
    }
    // online softmax (q fixed per lane)
    float mx = st[0][0];
    #pragma unroll
    for (int fc=0; fc<8; ++fc)
      #pragma unroll
      for (int r=0; r<4; r++) mx = fmaxf(mx, st[fc][r]);
    mx = fmaxf(mx, __shfl_xor(mx, 16));
    mx = fmaxf(mx, __shfl_xor(mx, 32));
    float mnew  = fmaxf(mrun, mx);
    float alpha = __expf(mrun - mnew);
    float sum = 0.f;
    #pragma unroll
    for (int fc=0; fc<8; ++fc)
      #pragma unroll
      for (int r=0; r<4; r++){
        float pv = __expf(st[fc][r] - mnew);
        st[fc][r] = pv;
        sum += pv;
      }
    sum += __shfl_xor(sum, 16);
    sum += __shfl_xor(sum, 32);
    lrun = lrun*alpha + sum;
    mrun = mnew;
    oacc[0][0]*=alpha; oacc[0][1]*=alpha; oacc[0][2]*=alpha; oacc[0][3]*=alpha;
    oacc[1][0]*=alpha; oacc[1][1]*=alpha; oacc[1][2]*=alpha; oacc[1][3]*=alpha;

    unsigned int u0[8], u1[8];
    #pragma unroll
    for (int fc=0; fc<8; ++fc){
      u0[fc] = pk_bf16(st[fc][0], st[fc][1]);
      u1[fc] = pk_bf16(st[fc][2], st[fc][3]);
    }
    #pragma unroll
    for (int ks=0; ks<4; ++ks){
      unsigned int e0 = u0[2*ks],   e1 = u1[2*ks];
      unsigned int o0 = u0[2*ks+1], o1 = u1[2*ks+1];
      unsigned int w0e = __shfl((int)e0, srcA), w1e = __shfl((int)e1, srcA);
      unsigned int w2e = __shfl((int)e0, srcB), w3e = __shfl((int)e1, srcB);
      unsigned int w0o = __shfl((int)o0, srcA), w1o = __shfl((int)o1, srcA);
      unsigned int w2o = __shfl((int)o0, srcB), w3o = __shfl((int)o1, srcB);
      union { unsigned int u[4]; bf16x8 v; } pa;
      pa.u[0] = hig ? w0o : w0e;
      pa.u[1] = hig ? w1o : w1e;
      pa.u[2] = hig ? w2o : w2e;
      pa.u[3] = hig ? w3o : w3e;
      #pragma unroll
      for (int dg=0; dg<2; ++dg){
        bf16x8 vb = *(const bf16x8*)&vtR[(dg*16 + c)*132 + ks*32 + g*8];
        oacc[dg] = __builtin_amdgcn_mfma_f32_16x16x32_bf16(vb, pa.v, oacc[dg], 0,0,0);
      }
    }

    __syncthreads();             // all reads of klR/vtR (this iter) and klW/vtW (prev) done
    if (more){
      *(uint4*)&klW[krow*36 + kseg*8] = kd;
      *(uint4*)&vtW[vd*132 + vgrp*8] = *(const uint4*)&tv[0];
    }
    __syncthreads();             // staged writes visible before next iteration reads
  }

  float rl = 1.0f / lrun;
  #pragma unroll
  for (int dg=0; dg<2; ++dg){
    uint2 pp;
    pp.x = pk_bf16(oacc[dg][0]*rl, oacc[dg][1]*rl);
    pp.y = pk_bf16(oacc[dg][2]*rl, oacc[dg][3]*rl);
    *(uint2*)&aout[((size_t)b*R_ + qrow)*D_ + h*32 + dg*16 + 4*g] = pp;
  }
}

// ---------------- fused residual + 2-partial reduce + bias + layernorm ----------------
__global__ __launch_bounds__(256) void resid_ln3(const float* __restrict__ xin,
    const unsigned short* __restrict__ pA, const unsigned short* __restrict__ pB,
    const float* __restrict__ bias, const float* __restrict__ gg, const float* __restrict__ bb,
    float* __restrict__ xout, unsigned short* __restrict__ xbf)
{
  int row = blockIdx.x*4 + (threadIdx.x >> 6);
  int lane = threadIdx.x & 63;
  size_t base = (size_t)row*D_ + lane*4;
  float4 a  = *(const float4*)&xin[base];
  ushort4 ua = *(const ushort4*)&pA[base];
  ushort4 ub = *(const ushort4*)&pB[base];
  float4 bs = *(const float4*)&bias[lane*4];
  float y0 = a.x + b2f(ua.x) + b2f(ub.x) + bs.x;
  float y1 = a.y + b2f(ua.y) + b2f(ub.y) + bs.y;
  float y2 = a.z + b2f(ua.z) + b2f(ub.z) + bs.z;
  float y3 = a.w + b2f(ua.w) + b2f(ub.w) + bs.w;
  float s = y0+y1+y2+y3;
  #pragma unroll
  for (int off=32; off>=1; off>>=1) s += __shfl_xor(s, off);
  float mu = s * (1.0f/256.0f);
  float d0=y0-mu, d1=y1-mu, d2=y2-mu, d3=y3-mu;
  float q = d0*d0 + d1*d1 + d2*d2 + d3*d3;
  #pragma unroll
  for (int off=32; off>=1; off>>=1) q += __shfl_xor(q, off);
  float rstd = rsqrtf(q*(1.0f/256.0f) + 1e-5f);
  float4 gv = *(const float4*)&gg[lane*4];
  float4 bv = *(const float4*)&bb[lane*4];
  float o0 = d0*rstd*gv.x + bv.x;
  float o1 = d1*rstd*gv.y + bv.y;
  float o2 = d2*rstd*gv.z + bv.z;
  float o3 = d3*rstd*gv.w + bv.w;
  float4 o; o.x=o0; o.y=o1; o.z=o2; o.w=o3;
  *(float4*)&xout[base] = o;
  ushort4 ob; ob.x=f2b(o0); ob.y=f2b(o1); ob.z=f2b(o2); ob.w=f2b(o3);
  *(ushort4*)&xbf[base] = ob;
}

// ---------------- driver ----------------
// ws layout (aliased in time, end ~87 MB):
//   0        : flag (256 B)
//   256      : maskf 32MB [dead after cvt_all] == hbuf 16MB (W1->W2) @256, ao 4MB @16777472
//   33554688 : maskbf 16MB (live all run)
//   50331904 : wqkv_b | 51118336: wo_b | 51380480: w1_b | 52429056: w2_b
//   53477632 : x_bf 4MB
//   57671936 : qkvb 12.6MB (QKV->attn)
//   70254848 : xf 8MB
//   78643456 : tmp 8MB (2 bf16 partials -> resid_ln3)
extern "C" void kernel_launch(void* const* d_in, const int* in_sizes, int n_in,
                              void* d_out, int out_size, void* d_ws, size_t ws_size,
                              hipStream_t stream)
{
  const float* node = (const float*)d_in[0];
  const int*   ei   = (const int*)d_in[1];
  const int*   rid  = (const int*)d_in[2];
  const unsigned char* km = (const unsigned char*)d_in[3];
  const float* rb   = (const float*)d_in[4];
  const float* Wqkv = (const float*)d_in[5];
  const float* bqkv = (const float*)d_in[6];
  const float* Wo   = (const float*)d_in[7];
  const float* bo   = (const float*)d_in[8];
  const float* ln1g = (const float*)d_in[9];
  const float* ln1b = (const float*)d_in[10];
  const float* W1   = (const float*)d_in[11];
  const float* b1   = (const float*)d_in[12];
  const float* W2   = (const float*)d_in[13];
  const float* b2   = (const float*)d_in[14];
  const float* ln2g = (const float*)d_in[15];
  const float* ln2b = (const float*)d_in[16];

  char* ws = (char*)d_ws;
  int*   flag   = (int*)ws;
  float* maskf  = (float*)(ws + 256);
  unsigned short* hbuf   = (unsigned short*)(ws + 256);
  unsigned short* ao     = (unsigned short*)(ws + 16777472);
  unsigned short* maskbf = (unsigned short*)(ws + 33554688);
  unsigned short* wqkv_b = (unsigned short*)(ws + 50331904);
  unsigned short* wo_b   = (unsigned short*)(ws + 51118336);
  unsigned short* w1_b   = (unsigned short*)(ws + 51380480);
  unsigned short* w2_b   = (unsigned short*)(ws + 52429056);
  unsigned short* x_bf   = (unsigned short*)(ws + 53477632);
  unsigned short* qkvb   = (unsigned short*)(ws + 57671936);
  float* xf   = (float*)(ws + 70254848);
  unsigned short* tmp = (unsigned short*)(ws + 78643456);

  hipMemsetAsync(flag, 0, 4, stream);
  detect_bool<<<1024, 256, 0, stream>>>(km, flag);
  mask_fill<<<8192, 256, 0, stream>>>(maskf);
  edge_base<<<1024, 256, 0, stream>>>(ei, km, flag, maskf);
  edge_bias<<<1024, 256, 0, stream>>>(ei, rid, km, flag, rb, maskf);
  cvt_all<<<11776, 256, 0, stream>>>(maskf, node, Wqkv, Wo, W1, W2,
                                     maskbf, x_bf, wqkv_b, wo_b, w1_b, w2_b);

  for (int l = 0; l < L_; ++l){
    gemm_bt<0,128,1><<<384, 256, 0, stream>>>(x_bf, wqkv_b + l*196608, bqkv + l*768, qkvb, 8192, 768, 256);
    attn_kernel<<<512, 512, 0, stream>>>(qkvb, maskbf, ao);
    gemm_bt<1,64,2><<<512, 256, 0, stream>>>(ao, wo_b + l*65536, bo + l*256, tmp, 8192, 256, 256);
    resid_ln3<<<2048, 256, 0, stream>>>(l==0 ? node : xf, tmp, tmp + 8192*256,
                                        bo + l*256, ln1g + l*256, ln1b + l*256, xf, x_bf);
    gemm_bt<2,128,1><<<512, 256, 0, stream>>>(x_bf, w1_b + l*262144, b1 + l*1024, hbuf, 8192, 1024, 256);
    gemm_bt<1,64,2><<<512, 256, 0, stream>>>(hbuf, w2_b + l*262144, b2 + l*256, tmp, 8192, 256, 1024);
    float* outp = (l == L_-1) ? (float*)d_out : xf;
    resid_ln3<<<2048, 256, 0, stream>>>(xf, tmp, tmp + 8192*256,
                                        b2 + l*256, ln2g + l*256, ln2b + l*256, outp, x_bf);
  }
}

// Round 9
// 335.350 us; speedup vs baseline: 1.2476x; 1.2476x over previous
//
#include <hip/hip_runtime.h>
#include <hip/hip_bf16.h>
#include <math.h>

#define B_ 8
#define R_ 1024
#define D_ 256
#define H_ 8
#define L_ 2
#define E_ 32768
#define FF_ 1024
#define NEGV (-1000000000.0f)

typedef short bf16x8 __attribute__((ext_vector_type(8)));
typedef float f32x4 __attribute__((ext_vector_type(4)));

__device__ __forceinline__ unsigned short f2b(float f){
  unsigned int u = __float_as_uint(f);
  u += 0x7fffu + ((u >> 16) & 1u);
  return (unsigned short)(u >> 16);
}
__device__ __forceinline__ float b2f(unsigned short u){
  return __uint_as_float((unsigned int)u << 16);
}
__device__ __forceinline__ unsigned int pk_bf16(float lo, float hi){
  unsigned int r;
  asm volatile("v_cvt_pk_bf16_f32 %0, %1, %2" : "=v"(r) : "v"(lo), "v"(hi));
  return r;
}

#define ASYNC_COPY16(gp, lp) \
  __builtin_amdgcn_global_load_lds((const __attribute__((address_space(1))) void*)(gp), \
                                   (__attribute__((address_space(3))) void*)(lp), 16, 0, 0)

// ---------------- mask construction (f32, exact reference semantics) ----------------

__global__ void detect_bool(const unsigned char* __restrict__ km, int* __restrict__ flag){
  int i = blockIdx.x*256 + threadIdx.x;
  int hit = ((i & 3) != 0) && (km[i] != 0);
  if (__ballot(hit) != 0ull && (threadIdx.x & 63) == 0) atomicOr(flag, 1);
}

__global__ void mask_fill(float* __restrict__ mask){
  size_t i = ((size_t)blockIdx.x*256 + threadIdx.x)*4;
  int row = (int)((i >> 10) & 1023);
  int col = (int)(i & 1023);
  float4 v;
  v.x = (row == col+0) ? 0.0f : NEGV;
  v.y = (row == col+1) ? 0.0f : NEGV;
  v.z = (row == col+2) ? 0.0f : NEGV;
  v.w = (row == col+3) ? 0.0f : NEGV;
  *(float4*)&mask[i] = v;
}

__device__ __forceinline__ int keep_of(const unsigned char* km, const int* flag, int tid){
  return flag[0] ? (int)km[tid] : (int)km[(size_t)tid*4];
}

__global__ void edge_base(const int* __restrict__ ei, const unsigned char* __restrict__ km,
                          const int* __restrict__ flag, float* __restrict__ mask){
  int tid = blockIdx.x*256 + threadIdx.x;
  int b = tid >> 15, e = tid & (E_-1);
  if (keep_of(km, flag, tid)){
    int src = ei[(size_t)b*2*E_ + e];
    int dst = ei[(size_t)b*2*E_ + E_ + e];
    mask[((size_t)b*R_ + src)*R_ + dst] = 0.0f;
  }
}

__global__ void edge_bias(const int* __restrict__ ei, const int* __restrict__ rid,
                          const unsigned char* __restrict__ km, const int* __restrict__ flag,
                          const float* __restrict__ rb, float* __restrict__ mask){
  int tid = blockIdx.x*256 + threadIdx.x;
  int b = tid >> 15, e = tid & (E_-1);
  if (keep_of(km, flag, tid)){
    int src = ei[(size_t)b*2*E_ + e];
    int dst = ei[(size_t)b*2*E_ + E_ + e];
    atomicAdd(&mask[((size_t)b*R_ + src)*R_ + dst], rb[rid[tid]]);
  }
}

// ---------------- fused dtype converts ----------------
__global__ __launch_bounds__(256) void cvt_all(const float* __restrict__ maskf,
    const float* __restrict__ node, const float* __restrict__ Wqkv,
    const float* __restrict__ Wo, const float* __restrict__ W1, const float* __restrict__ W2,
    unsigned short* __restrict__ maskbf, unsigned short* __restrict__ x_bf,
    unsigned short* __restrict__ wqkv_b, unsigned short* __restrict__ wo_b,
    unsigned short* __restrict__ w1_b, unsigned short* __restrict__ w2_b)
{
  int bid = blockIdx.x;
  const float* s; unsigned short* d; int base;
  if      (bid < 8192)  { s = maskf; d = maskbf; base = bid; }
  else if (bid < 10240) { s = node;  d = x_bf;   base = bid - 8192; }
  else if (bid < 10624) { s = Wqkv;  d = wqkv_b; base = bid - 10240; }
  else if (bid < 10752) { s = Wo;    d = wo_b;   base = bid - 10624; }
  else if (bid < 11264) { s = W1;    d = w1_b;   base = bid - 10752; }
  else                  { s = W2;    d = w2_b;   base = bid - 11264; }
  size_t i = ((size_t)base*256 + threadIdx.x)*4;
  float4 v = *(const float4*)&s[i];
  ushort4 o;
  o.x = f2b(v.x); o.y = f2b(v.y); o.z = f2b(v.z); o.w = f2b(v.w);
  *(ushort4*)&d[i] = o;
}

// ---------------- GEMM: C[M,N] = A[M,K] * B[N,K]^T ----------------
template<int MODE, int BN, int KS>
__global__ __launch_bounds__(256) void gemm_bt(const unsigned short* __restrict__ A,
    const unsigned short* __restrict__ Bw, const float* __restrict__ bias,
    void* __restrict__ Cout, int M, int N, int K)
{
  constexpr int NI = BN/32;
  constexpr int NCH = 8 + BN/16;
  constexpr int CPW = NCH/4;
  __shared__ unsigned short As[128*32];
  __shared__ unsigned short Bs[BN*32];
  const int nb = N / BN, mb = M >> 7;
  const int ks = blockIdx.x / (mb*nb);
  const int rem = blockIdx.x % (mb*nb);
  const int bm = rem / nb, bn = rem % nb;
  const int m0 = bm << 7, n0 = bn * BN;
  const int kbeg = ks * (K/KS), kend = kbeg + K/KS;
  const int t = threadIdx.x, lane = t & 63, wid = t >> 6;
  const int wr = wid >> 1, wc = wid & 1;
  const int c = lane & 15, g = lane >> 4;

  f32x4 zz = {0.f,0.f,0.f,0.f};
  f32x4 acc[4][NI];
  #pragma unroll
  for (int mi=0; mi<4; mi++)
    #pragma unroll
    for (int ni=0; ni<NI; ni++) acc[mi][ni] = zz;

  for (int k0 = kbeg; k0 < kend; k0 += 32){
    __syncthreads();
    #pragma unroll
    for (int it=0; it<CPW; ++it){
      int chunk = wid*CPW + it;
      int row16 = lane >> 2, seg = lane & 3;
      if (chunk < 8){
        int row = chunk*16 + row16;
        ASYNC_COPY16(A + (size_t)(m0+row)*K + k0 + seg*8, &As[chunk*512]);
      } else {
        int bch = chunk - 8;
        int row = bch*16 + row16;
        ASYNC_COPY16(Bw + (size_t)(n0+row)*K + k0 + seg*8, &Bs[bch*512]);
      }
    }
    __syncthreads();
    bf16x8 af[4], bfr[NI];
    #pragma unroll
    for (int mi=0; mi<4; mi++) af[mi]  = *(const bf16x8*)&As[(wr*64 + mi*16 + c)*32 + g*8];
    #pragma unroll
    for (int ni=0; ni<NI; ni++) bfr[ni] = *(const bf16x8*)&Bs[(wc*(BN/2) + ni*16 + c)*32 + g*8];
    #pragma unroll
    for (int mi=0; mi<4; mi++)
      #pragma unroll
      for (int ni=0; ni<NI; ni++)
        acc[mi][ni] = __builtin_amdgcn_mfma_f32_16x16x32_bf16(af[mi], bfr[ni], acc[mi][ni], 0,0,0);
  }

  unsigned short* outb = (unsigned short*)Cout + (size_t)ks*M*N;
  #pragma unroll
  for (int mi=0; mi<4; mi++){
    #pragma unroll
    for (int ni=0; ni<NI; ni++){
      int col = n0 + wc*(BN/2) + ni*16 + c;
      float bv = (MODE == 1) ? 0.0f : bias[col];
      #pragma unroll
      for (int r=0; r<4; r++){
        int row = m0 + wr*64 + mi*16 + 4*g + r;
        float v = acc[mi][ni][r] + bv;
        if (MODE == 2) v = 0.5f*v*(1.0f + erff(v*0.70710678f));
        outb[(size_t)row*N + col] = f2b(v);
      }
    }
  }
}

// ---------------- flash attention v5: R5 8-wave structure + bf16 mask + 36/132 ----
// 512 blocks x 512 thr (8 waves). Wave w owns q rows qt*128 + w*16 + c.
// S^T = mfma(K,Q): softmax lane-local in q. PV as O^T = mfma(V^T, P).
__global__ __launch_bounds__(512, 4) void attn_kernel(const unsigned short* __restrict__ qkv,
    const unsigned short* __restrict__ maskbf, unsigned short* __restrict__ aout)
{
  __shared__ unsigned short Klds[128*36];   // K tile [kv][d], stride 36
  __shared__ unsigned short VT[32*132];     // V^T tile [d][kv], stride 132
  const int blk = blockIdx.x;
  const int qt = blk & 7, h = (blk >> 3) & 7, b = blk >> 6;
  const int t = threadIdx.x, lane = t & 63, w = t >> 6;
  const int c = lane & 15, g = lane >> 4;
  const int qrow = qt*128 + w*16 + c;
  const size_t qbase = (size_t)b*R_*768;
  const float scale = 0.17677669529663689f;   // 1/sqrt(32)

  bf16x8 qf = *(const bf16x8*)&qkv[qbase + (size_t)qrow*768 + h*32 + g*8];

  f32x4 z4 = {0.f,0.f,0.f,0.f};
  f32x4 oacc[2] = {z4, z4};
  float mrun = -1e30f, lrun = 0.f;
  const int srcA = c + ((lane & 16) << 1);
  const int srcB = srcA + 16;
  const bool hig = (lane >= 32);

  for (int kt=0; kt<8; ++kt){
    const int kv0 = kt*128;
    __syncthreads();
    { // stage K: one uint4 per thread
      int row = t >> 2, seg = t & 3;
      uint4 kd = *(const uint4*)&qkv[qbase + (size_t)(kv0+row)*768 + 256 + h*32 + seg*8];
      *(uint4*)&Klds[row*36 + seg*8] = kd;
    }
    { // stage V transposed: 8 scalar loads + 1 uint4 write per thread
      int d = t & 31, grp = t >> 5;
      __align__(16) unsigned short tv[8];
      #pragma unroll
      for (int j=0; j<8; j++)
        tv[j] = qkv[qbase + (size_t)(kv0 + grp*8 + j)*768 + 512 + h*32 + d];
      *(uint4*)&VT[d*132 + grp*8] = *(const uint4*)&tv[0];
    }
    __syncthreads();

    f32x4 st[8];
    #pragma unroll
    for (int fc=0; fc<8; ++fc){
      bf16x8 kb = *(const bf16x8*)&Klds[(fc*16 + c)*36 + g*8];
      st[fc] = __builtin_amdgcn_mfma_f32_16x16x32_bf16(kb, qf, z4, 0,0,0);
    }
    const unsigned short* mrow = &maskbf[((size_t)b*R_ + qrow)*R_ + kv0];
    #pragma unroll
    for (int fc=0; fc<8; ++fc){
      ushort4 mu = *(const ushort4*)&mrow[fc*16 + 4*g];
      st[fc][0] = st[fc][0]*scale + b2f(mu.x);
      st[fc][1] = st[fc][1]*scale + b2f(mu.y);
      st[fc][2] = st[fc][2]*scale + b2f(mu.z);
      st[fc][3] = st[fc][3]*scale + b2f(mu.w);
    }
    float mx = st[0][0];
    #pragma unroll
    for (int fc=0; fc<8; ++fc)
      #pragma unroll
      for (int r=0; r<4; r++) mx = fmaxf(mx, st[fc][r]);
    mx = fmaxf(mx, __shfl_xor(mx, 16));
    mx = fmaxf(mx, __shfl_xor(mx, 32));
    float mnew  = fmaxf(mrun, mx);
    float alpha = __expf(mrun - mnew);
    float sum = 0.f;
    #pragma unroll
    for (int fc=0; fc<8; ++fc)
      #pragma unroll
      for (int r=0; r<4; r++){
        float pv = __expf(st[fc][r] - mnew);
        st[fc][r] = pv;
        sum += pv;
      }
    sum += __shfl_xor(sum, 16);
    sum += __shfl_xor(sum, 32);
    lrun = lrun*alpha + sum;
    mrun = mnew;
    oacc[0][0]*=alpha; oacc[0][1]*=alpha; oacc[0][2]*=alpha; oacc[0][3]*=alpha;
    oacc[1][0]*=alpha; oacc[1][1]*=alpha; oacc[1][2]*=alpha; oacc[1][3]*=alpha;

    unsigned int u0[8], u1[8];
    #pragma unroll
    for (int fc=0; fc<8; ++fc){
      u0[fc] = pk_bf16(st[fc][0], st[fc][1]);
      u1[fc] = pk_bf16(st[fc][2], st[fc][3]);
    }
    #pragma unroll
    for (int ks=0; ks<4; ++ks){
      unsigned int e0 = u0[2*ks],   e1 = u1[2*ks];
      unsigned int o0 = u0[2*ks+1], o1 = u1[2*ks+1];
      unsigned int w0e = __shfl((int)e0, srcA), w1e = __shfl((int)e1, srcA);
      unsigned int w2e = __shfl((int)e0, srcB), w3e = __shfl((int)e1, srcB);
      unsigned int w0o = __shfl((int)o0, srcA), w1o = __shfl((int)o1, srcA);
      unsigned int w2o = __shfl((int)o0, srcB), w3o = __shfl((int)o1, srcB);
      union { unsigned int u[4]; bf16x8 v; } pa;
      pa.u[0] = hig ? w0o : w0e;
      pa.u[1] = hig ? w1o : w1e;
      pa.u[2] = hig ? w2o : w2e;
      pa.u[3] = hig ? w3o : w3e;
      #pragma unroll
      for (int dg=0; dg<2; ++dg){
        bf16x8 vb = *(const bf16x8*)&VT[(dg*16 + c)*132 + ks*32 + g*8];
        oacc[dg] = __builtin_amdgcn_mfma_f32_16x16x32_bf16(vb, pa.v, oacc[dg], 0,0,0);
      }
    }
  }

  float rl = 1.0f / lrun;
  #pragma unroll
  for (int dg=0; dg<2; ++dg){
    uint2 pp;
    pp.x = pk_bf16(oacc[dg][0]*rl, oacc[dg][1]*rl);
    pp.y = pk_bf16(oacc[dg][2]*rl, oacc[dg][3]*rl);
    *(uint2*)&aout[((size_t)b*R_ + qrow)*D_ + h*32 + dg*16 + 4*g] = pp;
  }
}

// ---------------- fused residual + 2-partial reduce + bias + layernorm ----------------
__global__ __launch_bounds__(256) void resid_ln3(const float* __restrict__ xin,
    const unsigned short* __restrict__ pA, const unsigned short* __restrict__ pB,
    const float* __restrict__ bias, const float* __restrict__ gg, const float* __restrict__ bb,
    float* __restrict__ xout, unsigned short* __restrict__ xbf)
{
  int row = blockIdx.x*4 + (threadIdx.x >> 6);
  int lane = threadIdx.x & 63;
  size_t base = (size_t)row*D_ + lane*4;
  float4 a  = *(const float4*)&xin[base];
  ushort4 ua = *(const ushort4*)&pA[base];
  ushort4 ub = *(const ushort4*)&pB[base];
  float4 bs = *(const float4*)&bias[lane*4];
  float y0 = a.x + b2f(ua.x) + b2f(ub.x) + bs.x;
  float y1 = a.y + b2f(ua.y) + b2f(ub.y) + bs.y;
  float y2 = a.z + b2f(ua.z) + b2f(ub.z) + bs.z;
  float y3 = a.w + b2f(ua.w) + b2f(ub.w) + bs.w;
  float s = y0+y1+y2+y3;
  #pragma unroll
  for (int off=32; off>=1; off>>=1) s += __shfl_xor(s, off);
  float mu = s * (1.0f/256.0f);
  float d0=y0-mu, d1=y1-mu, d2=y2-mu, d3=y3-mu;
  float q = d0*d0 + d1*d1 + d2*d2 + d3*d3;
  #pragma unroll
  for (int off=32; off>=1; off>>=1) q += __shfl_xor(q, off);
  float rstd = rsqrtf(q*(1.0f/256.0f) + 1e-5f);
  float4 gv = *(const float4*)&gg[lane*4];
  float4 bv = *(const float4*)&bb[lane*4];
  float o0 = d0*rstd*gv.x + bv.x;
  float o1 = d1*rstd*gv.y + bv.y;
  float o2 = d2*rstd*gv.z + bv.z;
  float o3 = d3*rstd*gv.w + bv.w;
  float4 o; o.x=o0; o.y=o1; o.z=o2; o.w=o3;
  *(float4*)&xout[base] = o;
  ushort4 ob; ob.x=f2b(o0); ob.y=f2b(o1); ob.z=f2b(o2); ob.w=f2b(o3);
  *(ushort4*)&xbf[base] = ob;
}

// ---------------- driver ----------------
extern "C" void kernel_launch(void* const* d_in, const int* in_sizes, int n_in,
                              void* d_out, int out_size, void* d_ws, size_t ws_size,
                              hipStream_t stream)
{
  const float* node = (const float*)d_in[0];
  const int*   ei   = (const int*)d_in[1];
  const int*   rid  = (const int*)d_in[2];
  const unsigned char* km = (const unsigned char*)d_in[3];
  const float* rb   = (const float*)d_in[4];
  const float* Wqkv = (const float*)d_in[5];
  const float* bqkv = (const float*)d_in[6];
  const float* Wo   = (const float*)d_in[7];
  const float* bo   = (const float*)d_in[8];
  const float* ln1g = (const float*)d_in[9];
  const float* ln1b = (const float*)d_in[10];
  const float* W1   = (const float*)d_in[11];
  const float* b1   = (const float*)d_in[12];
  const float* W2   = (const float*)d_in[13];
  const float* b2   = (const float*)d_in[14];
  const float* ln2g = (const float*)d_in[15];
  const float* ln2b = (const float*)d_in[16];

  char* ws = (char*)d_ws;
  int*   flag   = (int*)ws;
  float* maskf  = (float*)(ws + 256);
  unsigned short* hbuf   = (unsigned short*)(ws + 256);
  unsigned short* ao     = (unsigned short*)(ws + 16777472);
  unsigned short* maskbf = (unsigned short*)(ws + 33554688);
  unsigned short* wqkv_b = (unsigned short*)(ws + 50331904);
  unsigned short* wo_b   = (unsigned short*)(ws + 51118336);
  unsigned short* w1_b   = (unsigned short*)(ws + 51380480);
  unsigned short* w2_b   = (unsigned short*)(ws + 52429056);
  unsigned short* x_bf   = (unsigned short*)(ws + 53477632);
  unsigned short* qkvb   = (unsigned short*)(ws + 57671936);
  float* xf   = (float*)(ws + 70254848);
  unsigned short* tmp = (unsigned short*)(ws + 78643456);

  hipMemsetAsync(flag, 0, 4, stream);
  detect_bool<<<1024, 256, 0, stream>>>(km, flag);
  mask_fill<<<8192, 256, 0, stream>>>(maskf);
  edge_base<<<1024, 256, 0, stream>>>(ei, km, flag, maskf);
  edge_bias<<<1024, 256, 0, stream>>>(ei, rid, km, flag, rb, maskf);
  cvt_all<<<11776, 256, 0, stream>>>(maskf, node, Wqkv, Wo, W1, W2,
                                     maskbf, x_bf, wqkv_b, wo_b, w1_b, w2_b);

  for (int l = 0; l < L_; ++l){
    gemm_bt<0,128,1><<<384, 256, 0, stream>>>(x_bf, wqkv_b + l*196608, bqkv + l*768, qkvb, 8192, 768, 256);
    attn_kernel<<<512, 512, 0, stream>>>(qkvb, maskbf, ao);
    gemm_bt<1,64,2><<<512, 256, 0, stream>>>(ao, wo_b + l*65536, bo + l*256, tmp, 8192, 256, 256);
    resid_ln3<<<2048, 256, 0, stream>>>(l==0 ? node : xf, tmp, tmp + 8192*256,
                                        bo + l*256, ln1g + l*256, ln1b + l*256, xf, x_bf);
    gemm_bt<2,128,1><<<512, 256, 0, stream>>>(x_bf, w1_b + l*262144, b1 + l*1024, hbuf, 8192, 1024, 256);
    gemm_bt<1,64,2><<<512, 256, 0, stream>>>(hbuf, w2_b + l*262144, b2 + l*256, tmp, 8192, 256, 1024);
    float* outp = (l == L_-1) ? (float*)d_out : xf;
    resid_ln3<<<2048, 256, 0, stream>>>(xf, tmp, tmp + 8192*256,
                                        b2 + l*256, ln2g + l*256, ln2b + l*256, outp, x_bf);
  }
}

// Round 11
// 314.308 us; speedup vs baseline: 1.3311x; 1.0669x over previous
//
#include <hip/hip_runtime.h>
#include <hip/hip_bf16.h>
#include <math.h>

#define B_ 8
#define R_ 1024
#define D_ 256
#define H_ 8
#define L_ 2
#define E_ 32768
#define FF_ 1024
#define NEGV (-1000000000.0f)

typedef short bf16x8 __attribute__((ext_vector_type(8)));
typedef float f32x4 __attribute__((ext_vector_type(4)));

__device__ __forceinline__ unsigned short f2b(float f){
  unsigned int u = __float_as_uint(f);
  u += 0x7fffu + ((u >> 16) & 1u);
  return (unsigned short)(u >> 16);
}
__device__ __forceinline__ float b2f(unsigned short u){
  return __uint_as_float((unsigned int)u << 16);
}
__device__ __forceinline__ unsigned int pk_bf16(float lo, float hi){
  unsigned int r;
  asm volatile("v_cvt_pk_bf16_f32 %0, %1, %2" : "=v"(r) : "v"(lo), "v"(hi));
  return r;
}

#define ASYNC_COPY16(gp, lp) \
  __builtin_amdgcn_global_load_lds((const __attribute__((address_space(1))) void*)(gp), \
                                   (__attribute__((address_space(3))) void*)(lp), 16, 0, 0)

// ---------------- mask construction (f32, exact reference semantics) ----------------

__global__ void detect_bool(const unsigned char* __restrict__ km, int* __restrict__ flag){
  int i = blockIdx.x*256 + threadIdx.x;
  int hit = ((i & 3) != 0) && (km[i] != 0);
  if (__ballot(hit) != 0ull && (threadIdx.x & 63) == 0) atomicOr(flag, 1);
}

__global__ void mask_fill(float* __restrict__ mask){
  size_t i = ((size_t)blockIdx.x*256 + threadIdx.x)*4;
  int row = (int)((i >> 10) & 1023);
  int col = (int)(i & 1023);
  float4 v;
  v.x = (row == col+0) ? 0.0f : NEGV;
  v.y = (row == col+1) ? 0.0f : NEGV;
  v.z = (row == col+2) ? 0.0f : NEGV;
  v.w = (row == col+3) ? 0.0f : NEGV;
  *(float4*)&mask[i] = v;
}

__device__ __forceinline__ int keep_of(const unsigned char* km, const int* flag, int tid){
  return flag[0] ? (int)km[tid] : (int)km[(size_t)tid*4];
}

__global__ void edge_base(const int* __restrict__ ei, const unsigned char* __restrict__ km,
                          const int* __restrict__ flag, float* __restrict__ mask){
  int tid = blockIdx.x*256 + threadIdx.x;
  int b = tid >> 15, e = tid & (E_-1);
  if (keep_of(km, flag, tid)){
    int src = ei[(size_t)b*2*E_ + e];
    int dst = ei[(size_t)b*2*E_ + E_ + e];
    mask[((size_t)b*R_ + src)*R_ + dst] = 0.0f;
  }
}

__global__ void edge_bias(const int* __restrict__ ei, const int* __restrict__ rid,
                          const unsigned char* __restrict__ km, const int* __restrict__ flag,
                          const float* __restrict__ rb, float* __restrict__ mask){
  int tid = blockIdx.x*256 + threadIdx.x;
  int b = tid >> 15, e = tid & (E_-1);
  if (keep_of(km, flag, tid)){
    int src = ei[(size_t)b*2*E_ + e];
    int dst = ei[(size_t)b*2*E_ + E_ + e];
    atomicAdd(&mask[((size_t)b*R_ + src)*R_ + dst], rb[rid[tid]]);
  }
}

// ---------------- fused dtype converts ----------------
__global__ __launch_bounds__(256) void cvt_all(const float* __restrict__ maskf,
    const float* __restrict__ node, const float* __restrict__ Wqkv,
    const float* __restrict__ Wo, const float* __restrict__ W1, const float* __restrict__ W2,
    unsigned short* __restrict__ maskbf, unsigned short* __restrict__ x_bf,
    unsigned short* __restrict__ wqkv_b, unsigned short* __restrict__ wo_b,
    unsigned short* __restrict__ w1_b, unsigned short* __restrict__ w2_b)
{
  int bid = blockIdx.x;
  const float* s; unsigned short* d; int base;
  if      (bid < 8192)  { s = maskf; d = maskbf; base = bid; }
  else if (bid < 10240) { s = node;  d = x_bf;   base = bid - 8192; }
  else if (bid < 10624) { s = Wqkv;  d = wqkv_b; base = bid - 10240; }
  else if (bid < 10752) { s = Wo;    d = wo_b;   base = bid - 10624; }
  else if (bid < 11264) { s = W1;    d = w1_b;   base = bid - 10752; }
  else                  { s = W2;    d = w2_b;   base = bid - 11264; }
  size_t i = ((size_t)base*256 + threadIdx.x)*4;
  float4 v = *(const float4*)&s[i];
  ushort4 o;
  o.x = f2b(v.x); o.y = f2b(v.y); o.z = f2b(v.z); o.w = f2b(v.w);
  *(ushort4*)&d[i] = o;
}

// ---------------- GEMM: C[M,N] = A[M,K] * B[N,K]^T ----------------
// MODE 0: bf16 out +bias | MODE 1: bf16 PARTIAL out, NO bias (split-K) | MODE 2: bf16 out gelu(+bias)
// 4 waves in 2x2; wave tile (BM/2)x(BN/2). XCD-aware swizzle (grid must be %8==0).
template<int MODE, int BM, int BN, int KS>
__global__ __launch_bounds__(256) void gemm_bt(const unsigned short* __restrict__ A,
    const unsigned short* __restrict__ Bw, const float* __restrict__ bias,
    void* __restrict__ Cout, int M, int N, int K)
{
  constexpr int MI = BM/32;
  constexpr int NI = BN/32;
  constexpr int NCH = (BM+BN)/16;   // 512-short staging chunks per k-step
  constexpr int CPW = NCH/4;        // chunks per wave
  constexpr int AC  = BM/16;        // A chunks
  __shared__ unsigned short As[BM*32];
  __shared__ unsigned short Bs[BN*32];
  const int T = gridDim.x;
  const int logical = (blockIdx.x & 7)*(T >> 3) + (blockIdx.x >> 3);  // XCD swizzle
  const int nb = N / BN, mb = M / BM;
  const int ks = logical / (mb*nb);
  const int rem = logical % (mb*nb);
  const int bm = rem / nb, bn = rem % nb;
  const int m0 = bm * BM, n0 = bn * BN;
  const int kbeg = ks * (K/KS), kend = kbeg + K/KS;
  const int t = threadIdx.x, lane = t & 63, wid = t >> 6;
  const int wr = wid >> 1, wc = wid & 1;
  const int c = lane & 15, g = lane >> 4;

  f32x4 zz = {0.f,0.f,0.f,0.f};
  f32x4 acc[MI][NI];
  #pragma unroll
  for (int mi=0; mi<MI; mi++)
    #pragma unroll
    for (int ni=0; ni<NI; ni++) acc[mi][ni] = zz;

  for (int k0 = kbeg; k0 < kend; k0 += 32){
    __syncthreads();
    #pragma unroll
    for (int it=0; it<CPW; ++it){
      int chunk = wid*CPW + it;          // wave-uniform
      int row16 = lane >> 2, seg = lane & 3;
      if (chunk < AC){
        int row = chunk*16 + row16;
        ASYNC_COPY16(A + (size_t)(m0+row)*K + k0 + seg*8, &As[chunk*512]);
      } else {
        int bch = chunk - AC;
        int row = bch*16 + row16;
        ASYNC_COPY16(Bw + (size_t)(n0+row)*K + k0 + seg*8, &Bs[bch*512]);
      }
    }
    __syncthreads();
    bf16x8 af[MI], bfr[NI];
    #pragma unroll
    for (int mi=0; mi<MI; mi++) af[mi]  = *(const bf16x8*)&As[(wr*(BM/2) + mi*16 + c)*32 + g*8];
    #pragma unroll
    for (int ni=0; ni<NI; ni++) bfr[ni] = *(const bf16x8*)&Bs[(wc*(BN/2) + ni*16 + c)*32 + g*8];
    #pragma unroll
    for (int mi=0; mi<MI; mi++)
      #pragma unroll
      for (int ni=0; ni<NI; ni++)
        acc[mi][ni] = __builtin_amdgcn_mfma_f32_16x16x32_bf16(af[mi], bfr[ni], acc[mi][ni], 0,0,0);
  }

  unsigned short* outb = (unsigned short*)Cout + (size_t)ks*M*N;
  #pragma unroll
  for (int mi=0; mi<MI; mi++){
    #pragma unroll
    for (int ni=0; ni<NI; ni++){
      int col = n0 + wc*(BN/2) + ni*16 + c;
      float bv = (MODE == 1) ? 0.0f : bias[col];
      #pragma unroll
      for (int r=0; r<4; r++){
        int row = m0 + wr*(BM/2) + mi*16 + 4*g + r;
        float v = acc[mi][ni][r] + bv;
        if (MODE == 2) v = 0.5f*v*(1.0f + erff(v*0.70710678f));
        outb[(size_t)row*N + col] = f2b(v);
      }
    }
  }
}

// ---------------- flash attention (R9 structure, unchanged) ----------
__global__ __launch_bounds__(512, 4) void attn_kernel(const unsigned short* __restrict__ qkv,
    const unsigned short* __restrict__ maskbf, unsigned short* __restrict__ aout)
{
  __shared__ unsigned short Klds[128*36];   // K tile [kv][d], stride 36
  __shared__ unsigned short VT[32*132];     // V^T tile [d][kv], stride 132
  const int blk = blockIdx.x;
  const int qt = blk & 7, h = (blk >> 3) & 7, b = blk >> 6;
  const int t = threadIdx.x, lane = t & 63, w = t >> 6;
  const int c = lane & 15, g = lane >> 4;
  const int qrow = qt*128 + w*16 + c;
  const size_t qbase = (size_t)b*R_*768;
  const float scale = 0.17677669529663689f;   // 1/sqrt(32)

  bf16x8 qf = *(const bf16x8*)&qkv[qbase + (size_t)qrow*768 + h*32 + g*8];

  f32x4 z4 = {0.f,0.f,0.f,0.f};
  f32x4 oacc[2] = {z4, z4};
  float mrun = -1e30f, lrun = 0.f;
  const int srcA = c + ((lane & 16) << 1);
  const int srcB = srcA + 16;
  const bool hig = (lane >= 32);

  for (int kt=0; kt<8; ++kt){
    const int kv0 = kt*128;
    __syncthreads();
    { // stage K: one uint4 per thread
      int row = t >> 2, seg = t & 3;
      uint4 kd = *(const uint4*)&qkv[qbase + (size_t)(kv0+row)*768 + 256 + h*32 + seg*8];
      *(uint4*)&Klds[row*36 + seg*8] = kd;
    }
    { // stage V transposed: 8 scalar loads + 1 uint4 write per thread
      int d = t & 31, grp = t >> 5;
      __align__(16) unsigned short tv[8];
      #pragma unroll
      for (int j=0; j<8; j++)
        tv[j] = qkv[qbase + (size_t)(kv0 + grp*8 + j)*768 + 512 + h*32 + d];
      *(uint4*)&VT[d*132 + grp*8] = *(const uint4*)&tv[0];
    }
    __syncthreads();

    f32x4 st[8];
    #pragma unroll
    for (int fc=0; fc<8; ++fc){
      bf16x8 kb = *(const bf16x8*)&Klds[(fc*16 + c)*36 + g*8];
      st[fc] = __builtin_amdgcn_mfma_f32_16x16x32_bf16(kb, qf, z4, 0,0,0);
    }
    const unsigned short* mrow = &maskbf[((size_t)b*R_ + qrow)*R_ + kv0];
    #pragma unroll
    for (int fc=0; fc<8; ++fc){
      ushort4 mu = *(const ushort4*)&mrow[fc*16 + 4*g];
      st[fc][0] = st[fc][0]*scale + b2f(mu.x);
      st[fc][1] = st[fc][1]*scale + b2f(mu.y);
      st[fc][2] = st[fc][2]*scale + b2f(mu.z);
      st[fc][3] = st[fc][3]*scale + b2f(mu.w);
    }
    float mx = st[0][0];
    #pragma unroll
    for (int fc=0; fc<8; ++fc)
      #pragma unroll
      for (int r=0; r<4; r++) mx = fmaxf(mx, st[fc][r]);
    mx = fmaxf(mx, __shfl_xor(mx, 16));
    mx = fmaxf(mx, __shfl_xor(mx, 32));
    float mnew  = fmaxf(mrun, mx);
    float alpha = __expf(mrun - mnew);
    float sum = 0.f;
    #pragma unroll
    for (int fc=0; fc<8; ++fc)
      #pragma unroll
      for (int r=0; r<4; r++){
        float pv = __expf(st[fc][r] - mnew);
        st[fc][r] = pv;
        sum += pv;
      }
    sum += __shfl_xor(sum, 16);
    sum += __shfl_xor(sum, 32);
    lrun = lrun*alpha + sum;
    mrun = mnew;
    oacc[0][0]*=alpha; oacc[0][1]*=alpha; oacc[0][2]*=alpha; oacc[0][3]*=alpha;
    oacc[1][0]*=alpha; oacc[1][1]*=alpha; oacc[1][2]*=alpha; oacc[1][3]*=alpha;

    unsigned int u0[8], u1[8];
    #pragma unroll
    for (int fc=0; fc<8; ++fc){
      u0[fc] = pk_bf16(st[fc][0], st[fc][1]);
      u1[fc] = pk_bf16(st[fc][2], st[fc][3]);
    }
    #pragma unroll
    for (int ks=0; ks<4; ++ks){
      unsigned int e0 = u0[2*ks],   e1 = u1[2*ks];
      unsigned int o0 = u0[2*ks+1], o1 = u1[2*ks+1];
      unsigned int w0e = __shfl((int)e0, srcA), w1e = __shfl((int)e1, srcA);
      unsigned int w2e = __shfl((int)e0, srcB), w3e = __shfl((int)e1, srcB);
      unsigned int w0o = __shfl((int)o0, srcA), w1o = __shfl((int)o1, srcA);
      unsigned int w2o = __shfl((int)o0, srcB), w3o = __shfl((int)o1, srcB);
      union { unsigned int u[4]; bf16x8 v; } pa;
      pa.u[0] = hig ? w0o : w0e;
      pa.u[1] = hig ? w1o : w1e;
      pa.u[2] = hig ? w2o : w2e;
      pa.u[3] = hig ? w3o : w3e;
      #pragma unroll
      for (int dg=0; dg<2; ++dg){
        bf16x8 vb = *(const bf16x8*)&VT[(dg*16 + c)*132 + ks*32 + g*8];
        oacc[dg] = __builtin_amdgcn_mfma_f32_16x16x32_bf16(vb, pa.v, oacc[dg], 0,0,0);
      }
    }
  }

  float rl = 1.0f / lrun;
  #pragma unroll
  for (int dg=0; dg<2; ++dg){
    uint2 pp;
    pp.x = pk_bf16(oacc[dg][0]*rl, oacc[dg][1]*rl);
    pp.y = pk_bf16(oacc[dg][2]*rl, oacc[dg][3]*rl);
    *(uint2*)&aout[((size_t)b*R_ + qrow)*D_ + h*32 + dg*16 + 4*g] = pp;
  }
}

// ---------------- fused residual + 2-partial reduce + bias + layernorm ----------------
__global__ __launch_bounds__(256) void resid_ln3(const float* __restrict__ xin,
    const unsigned short* __restrict__ pA, const unsigned short* __restrict__ pB,
    const float* __restrict__ bias, const float* __restrict__ gg, const float* __restrict__ bb,
    float* __restrict__ xout, unsigned short* __restrict__ xbf)
{
  int row = blockIdx.x*4 + (threadIdx.x >> 6);
  int lane = threadIdx.x & 63;
  size_t base = (size_t)row*D_ + lane*4;
  float4 a  = *(const float4*)&xin[base];
  ushort4 ua = *(const ushort4*)&pA[base];
  ushort4 ub = *(const ushort4*)&pB[base];
  float4 bs = *(const float4*)&bias[lane*4];
  float y0 = a.x + b2f(ua.x) + b2f(ub.x) + bs.x;
  float y1 = a.y + b2f(ua.y) + b2f(ub.y) + bs.y;
  float y2 = a.z + b2f(ua.z) + b2f(ub.z) + bs.z;
  float y3 = a.w + b2f(ua.w) + b2f(ub.w) + bs.w;
  float s = y0+y1+y2+y3;
  #pragma unroll
  for (int off=32; off>=1; off>>=1) s += __shfl_xor(s, off);
  float mu = s * (1.0f/256.0f);
  float d0=y0-mu, d1=y1-mu, d2=y2-mu, d3=y3-mu;
  float q = d0*d0 + d1*d1 + d2*d2 + d3*d3;
  #pragma unroll
  for (int off=32; off>=1; off>>=1) q += __shfl_xor(q, off);
  float rstd = rsqrtf(q*(1.0f/256.0f) + 1e-5f);
  float4 gv = *(const float4*)&gg[lane*4];
  float4 bv = *(const float4*)&bb[lane*4];
  float o0 = d0*rstd*gv.x + bv.x;
  float o1 = d1*rstd*gv.y + bv.y;
  float o2 = d2*rstd*gv.z + bv.z;
  float o3 = d3*rstd*gv.w + bv.w;
  float4 o; o.x=o0; o.y=o1; o.z=o2; o.w=o3;
  *(float4*)&xout[base] = o;
  ushort4 ob; ob.x=f2b(o0); ob.y=f2b(o1); ob.z=f2b(o2); ob.w=f2b(o3);
  *(ushort4*)&xbf[base] = ob;
}

// ---------------- driver ----------------
extern "C" void kernel_launch(void* const* d_in, const int* in_sizes, int n_in,
                              void* d_out, int out_size, void* d_ws, size_t ws_size,
                              hipStream_t stream)
{
  const float* node = (const float*)d_in[0];
  const int*   ei   = (const int*)d_in[1];
  const int*   rid  = (const int*)d_in[2];
  const unsigned char* km = (const unsigned char*)d_in[3];
  const float* rb   = (const float*)d_in[4];
  const float* Wqkv = (const float*)d_in[5];
  const float* bqkv = (const float*)d_in[6];
  const float* Wo   = (const float*)d_in[7];
  const float* bo   = (const float*)d_in[8];
  const float* ln1g = (const float*)d_in[9];
  const float* ln1b = (const float*)d_in[10];
  const float* W1   = (const float*)d_in[11];
  const float* b1   = (const float*)d_in[12];
  const float* W2   = (const float*)d_in[13];
  const float* b2   = (const float*)d_in[14];
  const float* ln2g = (const float*)d_in[15];
  const float* ln2b = (const float*)d_in[16];

  char* ws = (char*)d_ws;
  int*   flag   = (int*)ws;
  float* maskf  = (float*)(ws + 256);
  unsigned short* hbuf   = (unsigned short*)(ws + 256);
  unsigned short* ao     = (unsigned short*)(ws + 16777472);
  unsigned short* maskbf = (unsigned short*)(ws + 33554688);
  unsigned short* wqkv_b = (unsigned short*)(ws + 50331904);
  unsigned short* wo_b   = (unsigned short*)(ws + 51118336);
  unsigned short* w1_b   = (unsigned short*)(ws + 51380480);
  unsigned short* w2_b   = (unsigned short*)(ws + 52429056);
  unsigned short* x_bf   = (unsigned short*)(ws + 53477632);
  unsigned short* qkvb   = (unsigned short*)(ws + 57671936);
  float* xf   = (float*)(ws + 70254848);
  unsigned short* tmp = (unsigned short*)(ws + 78643456);

  hipMemsetAsync(flag, 0, 4, stream);
  detect_bool<<<1024, 256, 0, stream>>>(km, flag);
  mask_fill<<<8192, 256, 0, stream>>>(maskf);
  edge_base<<<1024, 256, 0, stream>>>(ei, km, flag, maskf);
  edge_bias<<<1024, 256, 0, stream>>>(ei, rid, km, flag, rb, maskf);
  cvt_all<<<11776, 256, 0, stream>>>(maskf, node, Wqkv, Wo, W1, W2,
                                     maskbf, x_bf, wqkv_b, wo_b, w1_b, w2_b);

  for (int l = 0; l < L_; ++l){
    gemm_bt<0,64,64,1><<<1536, 256, 0, stream>>>(x_bf, wqkv_b + l*196608, bqkv + l*768, qkvb, 8192, 768, 256);
    attn_kernel<<<512, 512, 0, stream>>>(qkvb, maskbf, ao);
    gemm_bt<1,64,64,2><<<1024, 256, 0, stream>>>(ao, wo_b + l*65536, bo + l*256, tmp, 8192, 256, 256);
    resid_ln3<<<2048, 256, 0, stream>>>(l==0 ? node : xf, tmp, tmp + 8192*256,
                                        bo + l*256, ln1g + l*256, ln1b + l*256, xf, x_bf);
    gemm_bt<2,64,64,1><<<2048, 256, 0, stream>>>(x_bf, w1_b + l*262144, b1 + l*1024, hbuf, 8192, 1024, 256);
    gemm_bt<1,64,64,2><<<1024, 256, 0, stream>>>(hbuf, w2_b + l*262144, b2 + l*256, tmp, 8192, 256, 1024);
    float* outp = (l == L_-1) ? (float*)d_out : xf;
    resid_ln3<<<2048, 256, 0, stream>>>(xf, tmp, tmp + 8192*256,
                                        b2 + l*256, ln2g + l*256, ln2b + l*256, outp, x_bf);
  }
}